// Round 4
// baseline (2173.068 us; speedup 1.0000x reference)
//
#include <hip/hip_runtime.h>
#include <hip/hip_bf16.h>

typedef unsigned int uint32;
typedef unsigned short ushort16;

#define HH 2
#define CC 64
#define DD 64
#define HC 128

__device__ __forceinline__ float bf2f(ushort16 u) {
    union { float f; uint32 u; } x; x.u = ((uint32)u) << 16; return x.f;
}
__device__ __forceinline__ ushort16 f2bf(float f) {
    union { float f; uint32 u; } x; x.f = f;
    uint32 u = x.u;
    u += 0x7FFFu + ((u >> 16) & 1u);   // round-to-nearest-even
    return (ushort16)(u >> 16);
}
// monotonic float<->uint encoding for atomicMax over signed floats
__device__ __forceinline__ uint32 encf(float f) {
    uint32 u = __float_as_uint(f);
    return (u & 0x80000000u) ? ~u : (u | 0x80000000u);
}
__device__ __forceinline__ float decf(uint32 e) {
    return (e & 0x80000000u) ? __uint_as_float(e & 0x7FFFFFFFu) : __uint_as_float(~e);
}
__device__ __forceinline__ int clampi(int v, int N) {
    return min(max(v, 0), N - 1);
}

// ---- K0: fold attention vectors into weight matrices ----
// v_src[h*64+d] = sum_c W_lin[d,h*64+c]*att_src[h,c]; same for dst/edge.
__global__ void k_fold(const float* W_lin, const float* att_src,
                       const float* att_dst, const float* W_edge,
                       const float* att_edge, float* vfold) {
    int t = threadIdx.x;            // 128 threads: t = h*64+d
    int h = t >> 6, d = t & 63;
    float vs = 0.f, vd = 0.f, ve = 0.f;
    for (int c = 0; c < CC; c++) {
        float wl = W_lin[d * HC + h * CC + c];
        vs += wl * att_src[h * CC + c];
        vd += wl * att_dst[h * CC + c];
        ve += W_edge[d * HC + h * CC + c] * att_edge[h * CC + c];
    }
    vfold[t] = vs; vfold[128 + t] = vd; vfold[256 + t] = ve;
}

// ---- K1: per-node logits: a_src[n,h]=right[n]·v_src[h], a_dst[n,h]=left[n]·v_dst[h]
__global__ __launch_bounds__(256) void k_node_logits(
    const float* right, const float* left, const float* vfold,
    float* a_src, float* a_dst, int N)
{
    __shared__ float vs[HC], vd[HC];
    if (threadIdx.x < HC) {
        vs[threadIdx.x] = vfold[threadIdx.x];
        vd[threadIdx.x] = vfold[HC + threadIdx.x];
    }
    __syncthreads();
    int w = threadIdx.x >> 6, lane = threadIdx.x & 63;
    for (int n = blockIdx.x * 4 + w; n < N; n += gridDim.x * 4) {
        float rl = right[(size_t)n * DD + lane];
        float ll = left[(size_t)n * DD + lane];
        float p0 = rl * vs[lane], p1 = rl * vs[64 + lane];
        float q0 = ll * vd[lane], q1 = ll * vd[64 + lane];
        #pragma unroll
        for (int m = 32; m >= 1; m >>= 1) {
            p0 += __shfl_xor(p0, m, 64); p1 += __shfl_xor(p1, m, 64);
            q0 += __shfl_xor(q0, m, 64); q1 += __shfl_xor(q1, m, 64);
        }
        if (lane == 0) {
            a_src[n * 2] = p0; a_src[n * 2 + 1] = p1;
            a_dst[n * 2] = q0; a_dst[n * 2 + 1] = q1;
        }
    }
}

// ---- K2: a_edge GEMV + alpha + leaky-relu -> att slot (fp32); seg atomicMax
// one wave per edge: 64 lanes read the 64-dim fp32 row (256B, fully coalesced)
__global__ __launch_bounds__(256) void k_edge_alpha(
    const float* edge_feat, const int* ei, const float* vfold,
    const float* a_src, const float* a_dst,
    float* att_slot, uint32* m_enc, int E, int N)
{
    __shared__ float vE[HC];
    if (threadIdx.x < HC) vE[threadIdx.x] = vfold[256 + threadIdx.x];
    __syncthreads();
    int lane = threadIdx.x & 63;
    int e = blockIdx.x * 4 + (threadIdx.x >> 6);
    if (e >= E) return;
    float fv = edge_feat[(size_t)e * DD + lane];
    float p0 = fv * vE[lane];
    float p1 = fv * vE[64 + lane];
    #pragma unroll
    for (int m = 32; m >= 1; m >>= 1) {
        p0 += __shfl_xor(p0, m, 64); p1 += __shfl_xor(p1, m, 64);
    }
    if (lane == 0) {
        int s  = clampi(ei[e], N);
        int d2 = clampi(ei[E + e], N);
        float al0 = a_src[s * 2]     + a_dst[d2 * 2]     + p0;
        float al1 = a_src[s * 2 + 1] + a_dst[d2 * 2 + 1] + p1;
        al0 = (al0 > 0.f) ? al0 : 0.2f * al0;
        al1 = (al1 > 0.f) ? al1 : 0.2f * al1;
        att_slot[e * 2] = al0; att_slot[e * 2 + 1] = al1;
        atomicMax(&m_enc[d2 * 2],     encf(al0));
        atomicMax(&m_enc[d2 * 2 + 1], encf(al1));
    }
}

// ---- K3: ex = exp(alpha - m[dst]) in place; segment atomicAdd sum ----
__global__ void k_exp_sum(const int* ei, const uint32* m_enc,
                          float* att_slot, float* ssum, int E, int N)
{
    int e = blockIdx.x * 256 + threadIdx.x;
    if (e >= E) return;
    int d2 = clampi(ei[E + e], N);
    float m0 = decf(m_enc[d2 * 2]);
    float m1 = decf(m_enc[d2 * 2 + 1]);
    if (!(fabsf(m0) < 1e30f)) m0 = 0.f;   // isfinite guard (kills NaN/Inf)
    if (!(fabsf(m1) < 1e30f)) m1 = 0.f;
    float e0 = __expf(fminf(att_slot[e * 2]     - m0, 30.f));
    float e1 = __expf(fminf(att_slot[e * 2 + 1] - m1, 30.f));
    att_slot[e * 2] = e0; att_slot[e * 2 + 1] = e1;
    atomicAdd(&ssum[d2 * 2],     e0);
    atomicAdd(&ssum[d2 * 2 + 1], e1);
}

// ---- K4: att = ex/(s+eps) in place; scatter att*right[src] into agg ----
// Linearity: sum_e att*(right[src]@W_lin) = (sum_e att*right[src]) @ W_lin per head.
__global__ __launch_bounds__(256) void k_scatter(
    const int* ei, const float* ssum, const float* right,
    float* att_slot, float* agg, int E, int N)
{
    int sub = threadIdx.x & 15;            // 16 threads per edge, 4 dims each
    int e = blockIdx.x * 16 + (threadIdx.x >> 4);
    if (e >= E) return;
    int s  = clampi(ei[e], N);
    int d2 = clampi(ei[E + e], N);
    float a0 = att_slot[e * 2]     / (ssum[d2 * 2]     + 1e-16f);
    float a1 = att_slot[e * 2 + 1] / (ssum[d2 * 2 + 1] + 1e-16f);
    // all 16 lanes of this edge-group are in one wave; reads above are issued
    // before this store in program order
    if (sub == 0) { att_slot[e * 2] = a0; att_slot[e * 2 + 1] = a1; }
    float4 v = ((const float4*)(right + (size_t)s * DD))[sub];
    float* dp0 = agg + (size_t)d2 * HC + sub * 4;      // head 0
    atomicAdd(dp0 + 0, a0 * v.x);
    atomicAdd(dp0 + 1, a0 * v.y);
    atomicAdd(dp0 + 2, a0 * v.z);
    atomicAdd(dp0 + 3, a0 * v.w);
    float* dp1 = dp0 + 64;                             // head 1
    atomicAdd(dp1 + 0, a1 * v.x);
    atomicAdd(dp1 + 1, a1 * v.y);
    atomicAdd(dp1 + 2, a1 * v.z);
    atomicAdd(dp1 + 3, a1 * v.w);
}

// ---- K5: fused: u = agg@W_lin + bias -> relu -> W_lt -> relu -> W_fm -> concat@W_pc
// weights cached in LDS as bf16 (56KB; precision ample vs absolute threshold)
__global__ __launch_bounds__(256) void k_post(
    const float* agg, const float* left, const float* W_lin,
    const float* bias_conv, const float* W_lt, const float* b_lt,
    const float* W_fm, const float* b_fm,
    const float* W_pc, const float* b_pc,
    float* out_lu, int N)
{
    __shared__ ushort16 sWlin[DD * HC];    // 16 KB
    __shared__ ushort16 sWlt[HC * CC];     // 16 KB
    __shared__ ushort16 sWfm[CC * CC];     // 8 KB
    __shared__ ushort16 sWpc[HC * CC];     // 16 KB
    __shared__ float sBc[HC], sBlt[CC], sBfm[CC], sBpc[CC];
    __shared__ float t0[4][HC], t1[4][CC], t2[4][CC];
    for (int i = threadIdx.x; i < DD * HC; i += 256) {
        sWlin[i] = f2bf(W_lin[i]);
        sWlt[i]  = f2bf(W_lt[i]);
        sWpc[i]  = f2bf(W_pc[i]);
    }
    for (int i = threadIdx.x; i < CC * CC; i += 256)
        sWfm[i] = f2bf(W_fm[i]);
    if (threadIdx.x < HC) sBc[threadIdx.x] = bias_conv[threadIdx.x];
    if (threadIdx.x < CC) {
        sBlt[threadIdx.x] = b_lt[threadIdx.x];
        sBfm[threadIdx.x] = b_fm[threadIdx.x];
        sBpc[threadIdx.x] = b_pc[threadIdx.x];
    }
    __syncthreads();
    int r = threadIdx.x >> 6;              // one wave per row
    int j = threadIdx.x & 63;
    for (int base = blockIdx.x * 4; base < N; base += gridDim.x * 4) {
        int n = base + r;
        bool act = (n < N);
        if (act) {
            const float* arow = agg + (size_t)n * HC;
            float ua = sBc[j], ub = sBc[64 + j];
            #pragma unroll
            for (int d = 0; d < DD; d++) {
                ua += arow[d]      * bf2f(sWlin[d * HC + j]);
                ub += arow[64 + d] * bf2f(sWlin[d * HC + 64 + j]);
            }
            t0[r][j] = fmaxf(ua, 0.f); t0[r][64 + j] = fmaxf(ub, 0.f);
        }
        __syncthreads();
        if (act) {
            float acc = sBlt[j];
            #pragma unroll
            for (int k = 0; k < HC; k++) acc += t0[r][k] * bf2f(sWlt[k * CC + j]);
            t1[r][j] = fmaxf(acc, 0.f);
        }
        __syncthreads();
        if (act) {
            float acc = sBfm[j];
            #pragma unroll
            for (int k = 0; k < CC; k++) acc += t1[r][k] * bf2f(sWfm[k * CC + j]);
            t2[r][j] = acc;
        }
        __syncthreads();
        if (act) {
            float acc = sBpc[j];
            const float* lrow = left + (size_t)n * DD;
            #pragma unroll
            for (int k = 0; k < CC; k++) acc += lrow[k] * bf2f(sWpc[k * CC + j]);
            #pragma unroll
            for (int k = 0; k < CC; k++) acc += t2[r][k] * bf2f(sWpc[(64 + k) * CC + j]);
            out_lu[(size_t)n * CC + j] = acc;
        }
        __syncthreads();
    }
}

// ---- K6: edge_index -> float copy into output slot 1 ----
__global__ void k_copy_idx(const int* ei, float* out, int n) {
    for (int i = blockIdx.x * blockDim.x + threadIdx.x; i < n;
         i += gridDim.x * blockDim.x)
        out[i] = (float)ei[i];
}

extern "C" void kernel_launch(void* const* d_in, const int* in_sizes, int n_in,
                              void* d_out, int out_size, void* d_ws, size_t ws_size,
                              hipStream_t stream) {
    const float* left      = (const float*)d_in[0];
    const int*   ei        = (const int*)d_in[1];
    const float* efeat     = (const float*)d_in[2];
    const float* right     = (const float*)d_in[3];
    const float* W_lin     = (const float*)d_in[5];
    const float* att_src   = (const float*)d_in[6];
    const float* att_dst   = (const float*)d_in[7];
    const float* W_edge    = (const float*)d_in[8];
    const float* att_edge  = (const float*)d_in[9];
    const float* bias_conv = (const float*)d_in[10];
    const float* W_lt      = (const float*)d_in[11];
    const float* b_lt      = (const float*)d_in[12];
    const float* W_fm      = (const float*)d_in[13];
    const float* b_fm      = (const float*)d_in[14];
    const float* W_pc      = (const float*)d_in[15];
    const float* b_pc      = (const float*)d_in[16];

    const int N = in_sizes[0] / DD;     // 50000
    const int E = in_sizes[2] / DD;     // 800000

    // ws layout (floats): vfold 384 + pad | a_src 2N | a_dst 2N |
    //                     m_enc 2N | ssum 2N | agg 128N   (~27.2 MB)
    float* ws     = (float*)d_ws;
    float* vfold  = ws;                              // 384 (+128 pad)
    float* a_src  = ws + 512;
    float* a_dst  = a_src + 2 * (size_t)N;
    uint32* m_enc = (uint32*)(a_dst + 2 * (size_t)N);
    float* ssum   = (float*)m_enc + 2 * (size_t)N;
    float* agg    = ssum + 2 * (size_t)N;            // N*128 fp32
    (void)ws_size; (void)n_in; (void)out_size;

    float* out_lu   = (float*)d_out;                 // [N,64]
    float* out_ei   = out_lu + (size_t)N * CC;       // [2,E] as float
    float* att_slot = out_ei + (size_t)2 * E;        // [E,2]: alpha -> ex -> att

    hipMemsetAsync(m_enc, 0, (size_t)4 * N * sizeof(float), stream);  // m_enc + ssum
    hipMemsetAsync(agg,   0, (size_t)N * HC * sizeof(float), stream);

    hipLaunchKernelGGL(k_fold, dim3(1), dim3(128), 0, stream,
                       W_lin, att_src, att_dst, W_edge, att_edge, vfold);
    hipLaunchKernelGGL(k_node_logits, dim3(1024), dim3(256), 0, stream,
                       right, left, vfold, a_src, a_dst, N);
    hipLaunchKernelGGL(k_edge_alpha, dim3((E + 3) / 4), dim3(256), 0, stream,
                       efeat, ei, vfold, a_src, a_dst, att_slot, m_enc, E, N);
    hipLaunchKernelGGL(k_exp_sum, dim3((E + 255) / 256), dim3(256), 0, stream,
                       ei, m_enc, att_slot, ssum, E, N);
    hipLaunchKernelGGL(k_scatter, dim3((E + 15) / 16), dim3(256), 0, stream,
                       ei, ssum, right, att_slot, agg, E, N);
    hipLaunchKernelGGL(k_post, dim3(512), dim3(256), 0, stream,
                       agg, left, W_lin, bias_conv, W_lt, b_lt, W_fm, b_fm,
                       W_pc, b_pc, out_lu, N);
    hipLaunchKernelGGL(k_copy_idx, dim3(1024), dim3(256), 0, stream,
                       ei, out_ei, 2 * E);
}